// Round 4
// baseline (518.772 us; speedup 1.0000x reference)
//
#include <hip/hip_runtime.h>
#include <hip/hip_bf16.h>
#include <stdint.h>

#define DM 1024
#define NH 16
#define HD 64
#define SEQ 2048
#define NB 2
#define NC 4            // attention k-chunks (partials)
#define KCH (SEQ / NC)  // 512

typedef __attribute__((ext_vector_type(8)))  __bf16 bf16x8;
typedef __attribute__((ext_vector_type(4)))  __bf16 bf16x4;
typedef __attribute__((ext_vector_type(4)))  float  f32x4;
typedef __attribute__((ext_vector_type(16))) float  f32x16;
typedef __attribute__((ext_vector_type(4)))  unsigned int uint4v;
typedef __attribute__((ext_vector_type(4)))  int    i32x4;

__device__ __forceinline__ f32x16 mfma32x32(bf16x8 a, bf16x8 b, f32x16 c) {
  return __builtin_amdgcn_mfma_f32_32x32x16_bf16(a, b, c, 0, 0, 0);
}
__device__ __forceinline__ f32x4 mfma16x16(bf16x8 a, bf16x8 b, f32x4 c) {
  return __builtin_amdgcn_mfma_f32_16x16x32_bf16(a, b, c, 0, 0, 0);
}
__device__ __forceinline__ unsigned pkbf(float a, float b) {
  unsigned short ua = __builtin_bit_cast(unsigned short, (__bf16)a);
  unsigned short ub = __builtin_bit_cast(unsigned short, (__bf16)b);
  return (unsigned)ua | ((unsigned)ub << 16);
}
__device__ __forceinline__ f32x16 zero16() {
  f32x16 z;
#pragma unroll
  for (int i = 0; i < 16; i++) z[i] = 0.0f;
  return z;
}

// ---------------- W transpose + bf16 convert: Wt[n][k] = (bf16)W[k][n] ----
__global__ void wconv_kernel(const float* __restrict__ Wq, const float* __restrict__ Wk,
                             const float* __restrict__ Wv, const float* __restrict__ Wo,
                             __bf16* __restrict__ Wt) {
  __shared__ float tile[32][33];
  const int which = blockIdx.z;
  const float* W = (which == 0) ? Wq : (which == 1) ? Wk : (which == 2) ? Wv : Wo;
  __bf16* out = Wt + (size_t)which * DM * DM;
  const int n0 = blockIdx.x * 32, k0 = blockIdx.y * 32;
  const int tx = threadIdx.x & 31, ty = threadIdx.x >> 5;  // ty 0..7
#pragma unroll
  for (int i = 0; i < 4; i++) {
    tile[ty + i * 8][tx] = W[(size_t)(k0 + ty + i * 8) * DM + n0 + tx];
  }
  __syncthreads();
#pragma unroll
  for (int i = 0; i < 4; i++) {
    out[(size_t)(n0 + ty + i * 8) * DM + k0 + tx] = (__bf16)tile[tx][ty + i * 8];
  }
}

// ---------------- Fused QKV projection GEMM (128x128 tile, z selects Q/K/V) --
// z=0: out Qh head-major [b,h,l,d]; z=1: Kh head-major; z=2: Vt transposed [b,h,d,l]
__global__ __launch_bounds__(256, 3)
void qkv_kernel(const float* __restrict__ Aq, const float* __restrict__ Ak,
                const float* __restrict__ Av, const __bf16* __restrict__ Wt,
                const float* __restrict__ bqv, const float* __restrict__ bkv,
                const float* __restrict__ bvv, __bf16* __restrict__ Qh,
                __bf16* __restrict__ Kh, __bf16* __restrict__ Vt) {
  __shared__ __bf16 Alds[128][40];
  __shared__ __bf16 Blds[128][40];
  const int z = blockIdx.z;
  const float* A = (z == 0) ? Aq : (z == 1) ? Ak : Av;
  const __bf16* Bt = Wt + (size_t)z * DM * DM;
  const float* bias = (z == 0) ? bqv : (z == 1) ? bkv : bvv;

  const int tid = threadIdx.x;
  const int l = tid & 63, w = tid >> 6;
  const int wm = w >> 1, wn = w & 1;
  const int r0 = blockIdx.x * 128, c0 = blockIdx.y * 128;

  f32x4 acc[4][4];
#pragma unroll
  for (int m = 0; m < 4; m++)
#pragma unroll
    for (int n = 0; n < 4; n++)
#pragma unroll
      for (int r = 0; r < 4; r++) acc[m][n][r] = 0.0f;

  const int ar = tid >> 2;  // 0..63 (two rows: ar, ar+64)
  const int aq = tid & 3;
  const int br = tid >> 1;  // 0..127
  const int bh = tid & 1;

  for (int kt = 0; kt < DM / 32; kt++) {
#pragma unroll
    for (int rep = 0; rep < 2; rep++) {
      const int row = ar + rep * 64;
      const float* src = A + (size_t)(r0 + row) * DM + kt * 32 + aq * 8;
      const f32x4 v0 = *(const f32x4*)(src);
      const f32x4 v1 = *(const f32x4*)(src + 4);
      bf16x8 av;
#pragma unroll
      for (int i = 0; i < 4; i++) { av[i] = (__bf16)v0[i]; av[4 + i] = (__bf16)v1[i]; }
      *(bf16x8*)&Alds[row][aq * 8] = av;
    }
    {
      const __bf16* bsrc = Bt + (size_t)(c0 + br) * DM + kt * 32 + bh * 16;
      bf16x8 v0 = *(const bf16x8*)bsrc;
      bf16x8 v1 = *(const bf16x8*)(bsrc + 8);
      *(bf16x8*)&Blds[br][bh * 16] = v0;
      *(bf16x8*)&Blds[br][bh * 16 + 8] = v1;
    }
    __syncthreads();
    bf16x8 af[4], bfr[4];
#pragma unroll
    for (int m = 0; m < 4; m++)
      af[m] = *(const bf16x8*)&Alds[wm * 64 + m * 16 + (l & 15)][(l >> 4) * 8];
#pragma unroll
    for (int n = 0; n < 4; n++)
      bfr[n] = *(const bf16x8*)&Blds[wn * 64 + n * 16 + (l & 15)][(l >> 4) * 8];
#pragma unroll
    for (int m = 0; m < 4; m++)
#pragma unroll
      for (int n = 0; n < 4; n++) acc[m][n] = mfma16x16(af[m], bfr[n], acc[m][n]);
    __syncthreads();
  }

  const int ccol = l & 15;
  const int crb = (l >> 4) * 4;
  __bf16* Ohm = (z == 0) ? Qh : Kh;
#pragma unroll
  for (int n = 0; n < 4; n++) {
    const int col = c0 + wn * 64 + n * 16 + ccol;
    const float bv = bias[col];
    const int h = col >> 6, d = col & 63;
#pragma unroll
    for (int m = 0; m < 4; m++) {
      const int row = r0 + wm * 64 + m * 16 + crb;
      f32x4 v = acc[m][n];
#pragma unroll
      for (int r = 0; r < 4; r++) v[r] += bv;
      if (z < 2) {  // head-major [b,h,l,d]
#pragma unroll
        for (int r = 0; r < 4; r++) {
          const int rr = row + r; const int bb = rr >> 11; const int ll = rr & 2047;
          Ohm[(((size_t)bb * NH + h) * SEQ + ll) * HD + d] = (__bf16)v[r];
        }
      } else {  // V^T [b,h,d,l], 4 consecutive l -> 8B store
        const int bb = row >> 11, ll = row & 2047;
        bf16x4 pk;
#pragma unroll
        for (int r = 0; r < 4; r++) pk[r] = (__bf16)v[r];
        *(bf16x4*)&Vt[(((size_t)bb * NH + h) * HD + d) * SEQ + ll] = pk;
      }
    }
  }
}

// ---------------- Attention with softmax over HEADS ------------------------
// E' = mfma(K, Q^T): C layout row = k_local = (r&3)+8*(r>>2)+4*hi, col = q_local = l&31
__device__ __forceinline__ void process_head(const float (&pp)[16], const float (&rd)[16],
                                             int hi, int lq, int k0,
                                             const __bf16* __restrict__ vbase,
                                             f32x16& x0, f32x16& x1) {
  unsigned u[8];
#pragma unroll
  for (int j = 0; j < 8; j++) {
    const float a = pp[2 * j] * rd[2 * j];
    const float b = pp[2 * j + 1] * rd[2 * j + 1];
    u[j] = pkbf(a, b);
  }
  unsigned t[8];
#pragma unroll
  for (int j = 0; j < 8; j++) t[j] = (unsigned)__shfl_xor((int)u[j], 32, 64);
  const unsigned w0 = hi ? t[2] : u[0];
  const unsigned w1 = hi ? t[3] : u[1];
  const unsigned w2 = hi ? u[2] : t[0];
  const unsigned w3 = hi ? u[3] : t[1];
  const unsigned w4 = hi ? t[6] : u[4];
  const unsigned w5 = hi ? t[7] : u[5];
  const unsigned w6 = hi ? u[6] : t[4];
  const unsigned w7 = hi ? u[7] : t[5];
  const uint4v s0v = {w0, w1, w2, w3};
  const uint4v s1v = {w4, w5, w6, w7};
  const bf16x8 pa0 = __builtin_bit_cast(bf16x8, s0v);
  const bf16x8 pa1 = __builtin_bit_cast(bf16x8, s1v);
  const __bf16* vp = vbase + (size_t)lq * SEQ + k0 + hi * 8;
  bf16x8 vf;
  vf = *(const bf16x8*)(vp);                         x0 = mfma32x32(pa0, vf, x0);
  vf = *(const bf16x8*)(vp + 16);                    x0 = mfma32x32(pa1, vf, x0);
  vf = *(const bf16x8*)(vp + (size_t)32 * SEQ);      x1 = mfma32x32(pa0, vf, x1);
  vf = *(const bf16x8*)(vp + (size_t)32 * SEQ + 16); x1 = mfma32x32(pa1, vf, x1);
}

__global__ __launch_bounds__(512, 4)
void attn_kernel(const __bf16* __restrict__ Qh, const __bf16* __restrict__ Kh,
                 const __bf16* __restrict__ Vt, const int* __restrict__ mask,
                 __bf16* __restrict__ Xp) {
  __shared__ float part[8 * 64 * 16];   // [wave][lane][reg] partial exp-sums (32 KB)
  __shared__ float Dbuf[1024];          // per-(lane,reg) denominators
  __shared__ unsigned mbits[32 * 17];   // mask bitwords [q][kword], padded 17
  const int tid = threadIdx.x;
  const int l = tid & 63;
  const int w = tid >> 6;
  const int lq = l & 31;
  const int hi = l >> 5;
  const int qt = blockIdx.x, b = blockIdx.y, c = blockIdx.z;
  const int q0 = qt * 32;
  const int h0 = w * 2;

  {  // stage mask chunk as bits: 32 q x KCH k -> 32 x (KCH/32) words
    const int qq = tid >> 4, wi = tid & 15;  // wi 0..15 covers KCH/32=16 words
    const i32x4* mp = (const i32x4*)(mask + ((size_t)b * SEQ + q0 + qq) * SEQ +
                                     (size_t)c * KCH + wi * 32);
    unsigned word = 0;
#pragma unroll
    for (int j = 0; j < 8; j++) {
      const i32x4 v = mp[j];
      word |= (v.x ? 1u : 0u) << (4 * j);
      word |= (v.y ? 1u : 0u) << (4 * j + 1);
      word |= (v.z ? 1u : 0u) << (4 * j + 2);
      word |= (v.w ? 1u : 0u) << (4 * j + 3);
    }
    mbits[qq * 17 + wi] = word;
  }

  // Preload Q as B-fragments: lane holds Q[b,h,q0+lq, ch*16+hi*8 .. +7]
  bf16x8 qf[2][4];
#pragma unroll
  for (int hh = 0; hh < 2; hh++) {
    const __bf16* qp = Qh + (((size_t)b * NH + h0 + hh) * SEQ + q0 + lq) * HD + hi * 8;
#pragma unroll
    for (int ch = 0; ch < 4; ch++) qf[hh][ch] = *(const bf16x8*)(qp + ch * 16);
  }
  f32x16 xacc[2][2];
#pragma unroll
  for (int i = 0; i < 2; i++)
#pragma unroll
    for (int j = 0; j < 2; j++) xacc[i][j] = zero16();

  const __bf16* kbase0 = Kh + ((size_t)b * NH + h0) * SEQ * HD;
  const __bf16* kbase1 = Kh + ((size_t)b * NH + h0 + 1) * SEQ * HD;
  const __bf16* vbase0 = Vt + ((size_t)b * NH + h0) * HD * SEQ;
  const __bf16* vbase1 = Vt + ((size_t)b * NH + h0 + 1) * HD * SEQ;

  __syncthreads();  // mbits ready

  for (int kt = 0; kt < KCH / 32; kt++) {
    const int k0 = c * KCH + kt * 32;

    f32x16 e0 = zero16(), e1 = zero16();
#pragma unroll
    for (int ch = 0; ch < 4; ch++) {
      const bf16x8 kf = *(const bf16x8*)(kbase0 + ((size_t)(k0 + lq)) * HD + ch * 16 + hi * 8);
      e0 = mfma32x32(kf, qf[0][ch], e0);
    }
#pragma unroll
    for (int ch = 0; ch < 4; ch++) {
      const bf16x8 kf = *(const bf16x8*)(kbase1 + ((size_t)(k0 + lq)) * HD + ch * 16 + hi * 8);
      e1 = mfma32x32(kf, qf[1][ch], e1);
    }
    const unsigned mword = mbits[lq * 17 + kt];
    float p0[16], p1[16], s4[16];
#pragma unroll
    for (int r = 0; r < 16; r++) {
      const int crow = (r & 3) + 8 * (r >> 2) + 4 * hi;
      const float bv = ((mword >> crow) & 1u) ? 0.0f : -1e10f;
      const float a0 = fmaf(e0[r], 0.125f, bv);  // /sqrt(64) + mask bias (exact)
      const float a1 = fmaf(e1[r], 0.125f, bv);
      p0[r] = __expf(a0);
      p1[r] = __expf(a1);
      s4[r] = p0[r] + p1[r];
    }
    {
      float* pw = &part[(unsigned)((w << 6) | l) * 16];
#pragma unroll
      for (int i = 0; i < 4; i++) {
        f32x4 v;
#pragma unroll
        for (int j = 0; j < 4; j++) v[j] = s4[4 * i + j];
        *(f32x4*)(pw + 4 * i) = v;
      }
    }
    __syncthreads();
    {  // cross-wave reduce over 8 waves (16 heads) -> denominators
      const int p2 = tid * 2;
      float da = 0.0f, db = 0.0f;
#pragma unroll
      for (int w2 = 0; w2 < 8; w2++) {
        da += part[w2 * 1024 + p2];
        db += part[w2 * 1024 + p2 + 1];
      }
      Dbuf[p2] = da;
      Dbuf[p2 + 1] = db;
    }
    __syncthreads();
    float rd[16];
#pragma unroll
    for (int i = 0; i < 4; i++) {
      const f32x4 dv = *(const f32x4*)&Dbuf[l * 16 + i * 4];
#pragma unroll
      for (int j = 0; j < 4; j++) rd[4 * i + j] = __builtin_amdgcn_rcpf(dv[j]);
    }
    process_head(p0, rd, hi, lq, k0, vbase0, xacc[0][0], xacc[0][1]);
    process_head(p1, rd, hi, lq, k0, vbase1, xacc[1][0], xacc[1][1]);
  }

  // Write partial X (bf16): Xp[c][b][h][q][d]
  const size_t XCH = (size_t)NB * NH * SEQ * HD;
#pragma unroll
  for (int hh = 0; hh < 2; hh++) {
    __bf16* xo = Xp + (size_t)c * XCH +
                 (((size_t)b * NH + h0 + hh) * SEQ + q0) * HD;
#pragma unroll
    for (int dt = 0; dt < 2; dt++) {
#pragma unroll
      for (int r = 0; r < 16; r++) {
        const int crow = (r & 3) + 8 * (r >> 2) + 4 * hi;
        xo[(size_t)crow * HD + dt * 32 + lq] = (__bf16)xacc[hh][dt][r];
      }
    }
  }
}

// ---------------- O-GEMM: Out[4096,1024] = (sum_c Xp_c)[head-major] @ WoT + bo
// Tile 64x128, 4 waves (each 64m x 32n), grid (64, 8) = 512 blocks
__global__ __launch_bounds__(256, 4)
void ogemm_kernel(const __bf16* __restrict__ Xp, const __bf16* __restrict__ Bt,
                  const float* __restrict__ bias, float* __restrict__ Out) {
  __shared__ __bf16 Alds[64][40];
  __shared__ __bf16 Blds[128][40];
  const int tid = threadIdx.x;
  const int l = tid & 63, w = tid >> 6;  // w -> n-offset w*32
  const int r0 = blockIdx.x * 64, c0 = blockIdx.y * 128;

  f32x4 acc[4][2];
#pragma unroll
  for (int m = 0; m < 4; m++)
#pragma unroll
    for (int n = 0; n < 2; n++)
#pragma unroll
      for (int r = 0; r < 4; r++) acc[m][n][r] = 0.0f;

  const int ar = tid >> 2, aq = tid & 3;
  const int br = tid >> 1, bh = tid & 1;
  const size_t PART = (size_t)NB * NH * SEQ * HD;
  const int rr = r0 + ar;
  const int bb = rr >> 11, ll = rr & 2047;

  for (int kt = 0; kt < DM / 32; kt++) {
    {
      const int cc = kt * 32 + aq * 8;
      const int h = cc >> 6, d = cc & 63;
      const size_t off = (((size_t)bb * NH + h) * SEQ + ll) * HD + d;
      float fv[8];
#pragma unroll
      for (int i = 0; i < 8; i++) fv[i] = 0.0f;
#pragma unroll
      for (int c = 0; c < NC; c++) {
        const bf16x8 v = *(const bf16x8*)(Xp + (size_t)c * PART + off);
#pragma unroll
        for (int i = 0; i < 8; i++) fv[i] += (float)v[i];
      }
      bf16x8 av;
#pragma unroll
      for (int i = 0; i < 8; i++) av[i] = (__bf16)fv[i];
      *(bf16x8*)&Alds[ar][aq * 8] = av;
    }
    {
      const __bf16* bsrc = Bt + (size_t)(c0 + br) * DM + kt * 32 + bh * 16;
      bf16x8 v0 = *(const bf16x8*)bsrc;
      bf16x8 v1 = *(const bf16x8*)(bsrc + 8);
      *(bf16x8*)&Blds[br][bh * 16] = v0;
      *(bf16x8*)&Blds[br][bh * 16 + 8] = v1;
    }
    __syncthreads();
    bf16x8 af[4], bfr[2];
#pragma unroll
    for (int m = 0; m < 4; m++)
      af[m] = *(const bf16x8*)&Alds[m * 16 + (l & 15)][(l >> 4) * 8];
#pragma unroll
    for (int n = 0; n < 2; n++)
      bfr[n] = *(const bf16x8*)&Blds[w * 32 + n * 16 + (l & 15)][(l >> 4) * 8];
#pragma unroll
    for (int m = 0; m < 4; m++)
#pragma unroll
      for (int n = 0; n < 2; n++) acc[m][n] = mfma16x16(af[m], bfr[n], acc[m][n]);
    __syncthreads();
  }

  const int ccol = l & 15;
  const int crb = (l >> 4) * 4;
#pragma unroll
  for (int n = 0; n < 2; n++) {
    const int col = c0 + w * 32 + n * 16 + ccol;
    const float bv = bias[col];
#pragma unroll
    for (int m = 0; m < 4; m++) {
      const int row = r0 + m * 16 + crb;
      f32x4 v = acc[m][n];
#pragma unroll
      for (int r = 0; r < 4; r++) Out[(size_t)(row + r) * DM + col] = v[r] + bv;
    }
  }
}

// ---------------------------------------------------------------------------
extern "C" void kernel_launch(void* const* d_in, const int* in_sizes, int n_in,
                              void* d_out, int out_size, void* d_ws, size_t ws_size,
                              hipStream_t stream) {
  const float* q = (const float*)d_in[0];
  const float* k = (const float*)d_in[1];
  const float* v = (const float*)d_in[2];
  const int* msk = (const int*)d_in[3];
  const float* Wq = (const float*)d_in[4];
  const float* bq = (const float*)d_in[5];
  const float* Wk = (const float*)d_in[6];
  const float* bk = (const float*)d_in[7];
  const float* Wv = (const float*)d_in[8];
  const float* bv = (const float*)d_in[9];
  const float* Wo = (const float*)d_in[10];
  const float* bo = (const float*)d_in[11];

  char* ws = (char*)d_ws;
  const size_t MB = 1024 * 1024;
  if (ws_size < 64 * MB) return;  // visible failure rather than OOB
  __bf16* Wt = (__bf16*)(ws);             // 4 x 1M bf16 (8 MiB)
  __bf16* Qh = (__bf16*)(ws + 8 * MB);    // [b,h,l,d] 8 MiB
  __bf16* Kh = (__bf16*)(ws + 16 * MB);   // [b,h,l,d] 8 MiB
  __bf16* Vt = (__bf16*)(ws + 24 * MB);   // [b,h,d,l] 8 MiB
  __bf16* Xp = (__bf16*)(ws + 32 * MB);   // NC chunks x 8 MiB bf16 partials

  wconv_kernel<<<dim3(32, 32, 4), 256, 0, stream>>>(Wq, Wk, Wv, Wo, Wt);
  qkv_kernel<<<dim3(32, 8, 3), 256, 0, stream>>>(q, k, v, Wt, bq, bk, bv, Qh, Kh, Vt);
  attn_kernel<<<dim3(64, 2, NC), 512, 0, stream>>>(Qh, Kh, Vt, msk, Xp);
  ogemm_kernel<<<dim3(64, 8), 256, 0, stream>>>(Xp, Wt + (size_t)3 * DM * DM, bo, (float*)d_out);
}

// Round 6
// 511.308 us; speedup vs baseline: 1.0146x; 1.0146x over previous
//
#include <hip/hip_runtime.h>
#include <hip/hip_bf16.h>
#include <stdint.h>

#define DM 1024
#define NH 16
#define HD 64
#define SEQ 2048
#define NB 2

typedef __attribute__((ext_vector_type(8)))  __bf16 bf16x8;
typedef __attribute__((ext_vector_type(4)))  __bf16 bf16x4;
typedef __attribute__((ext_vector_type(4)))  float  f32x4;
typedef __attribute__((ext_vector_type(16))) float  f32x16;
typedef __attribute__((ext_vector_type(4)))  unsigned int uint4v;
typedef __attribute__((ext_vector_type(4)))  int    i32x4;

__device__ __forceinline__ f32x16 mfma32x32(bf16x8 a, bf16x8 b, f32x16 c) {
  return __builtin_amdgcn_mfma_f32_32x32x16_bf16(a, b, c, 0, 0, 0);
}
__device__ __forceinline__ f32x4 mfma16x16(bf16x8 a, bf16x8 b, f32x4 c) {
  return __builtin_amdgcn_mfma_f32_16x16x32_bf16(a, b, c, 0, 0, 0);
}
__device__ __forceinline__ unsigned pkbf(float a, float b) {
  unsigned short ua = __builtin_bit_cast(unsigned short, (__bf16)a);
  unsigned short ub = __builtin_bit_cast(unsigned short, (__bf16)b);
  return (unsigned)ua | ((unsigned)ub << 16);
}
__device__ __forceinline__ f32x16 zero16() {
  f32x16 z;
#pragma unroll
  for (int i = 0; i < 16; i++) z[i] = 0.0f;
  return z;
}

// ---------------- W transpose + bf16 convert: Wt[n][k] = (bf16)W[k][n] ----
__global__ void wconv_kernel(const float* __restrict__ Wq, const float* __restrict__ Wk,
                             const float* __restrict__ Wv, const float* __restrict__ Wo,
                             __bf16* __restrict__ Wt) {
  __shared__ float tile[32][33];
  const int which = blockIdx.z;
  const float* W = (which == 0) ? Wq : (which == 1) ? Wk : (which == 2) ? Wv : Wo;
  __bf16* out = Wt + (size_t)which * DM * DM;
  const int n0 = blockIdx.x * 32, k0 = blockIdx.y * 32;
  const int tx = threadIdx.x & 31, ty = threadIdx.x >> 5;  // ty 0..7
#pragma unroll
  for (int i = 0; i < 4; i++) {
    tile[ty + i * 8][tx] = W[(size_t)(k0 + ty + i * 8) * DM + n0 + tx];
  }
  __syncthreads();
#pragma unroll
  for (int i = 0; i < 4; i++) {
    out[(size_t)(n0 + ty + i * 8) * DM + k0 + tx] = (__bf16)tile[tx][ty + i * 8];
  }
}

// ---------------- Fused QKV projection GEMM (128x128 tile, z selects Q/K/V) --
__global__ __launch_bounds__(256, 3)
void qkv_kernel(const float* __restrict__ Aq, const float* __restrict__ Ak,
                const float* __restrict__ Av, const __bf16* __restrict__ Wt,
                const float* __restrict__ bqv, const float* __restrict__ bkv,
                const float* __restrict__ bvv, __bf16* __restrict__ Qh,
                __bf16* __restrict__ Kh, __bf16* __restrict__ Vt) {
  __shared__ __bf16 Alds[128][40];
  __shared__ __bf16 Blds[128][40];
  const int z = blockIdx.z;
  const float* A = (z == 0) ? Aq : (z == 1) ? Ak : Av;
  const __bf16* Bt = Wt + (size_t)z * DM * DM;
  const float* bias = (z == 0) ? bqv : (z == 1) ? bkv : bvv;

  const int tid = threadIdx.x;
  const int l = tid & 63, w = tid >> 6;
  const int wm = w >> 1, wn = w & 1;
  const int r0 = blockIdx.x * 128, c0 = blockIdx.y * 128;

  f32x4 acc[4][4];
#pragma unroll
  for (int m = 0; m < 4; m++)
#pragma unroll
    for (int n = 0; n < 4; n++)
#pragma unroll
      for (int r = 0; r < 4; r++) acc[m][n][r] = 0.0f;

  const int ar = tid >> 2;  // 0..63 (two rows: ar, ar+64)
  const int aq = tid & 3;
  const int br = tid >> 1;  // 0..127
  const int bh = tid & 1;

  for (int kt = 0; kt < DM / 32; kt++) {
#pragma unroll
    for (int rep = 0; rep < 2; rep++) {
      const int row = ar + rep * 64;
      const float* src = A + (size_t)(r0 + row) * DM + kt * 32 + aq * 8;
      const f32x4 v0 = *(const f32x4*)(src);
      const f32x4 v1 = *(const f32x4*)(src + 4);
      bf16x8 av;
#pragma unroll
      for (int i = 0; i < 4; i++) { av[i] = (__bf16)v0[i]; av[4 + i] = (__bf16)v1[i]; }
      *(bf16x8*)&Alds[row][aq * 8] = av;
    }
    {
      const __bf16* bsrc = Bt + (size_t)(c0 + br) * DM + kt * 32 + bh * 16;
      bf16x8 v0 = *(const bf16x8*)bsrc;
      bf16x8 v1 = *(const bf16x8*)(bsrc + 8);
      *(bf16x8*)&Blds[br][bh * 16] = v0;
      *(bf16x8*)&Blds[br][bh * 16 + 8] = v1;
    }
    __syncthreads();
    bf16x8 af[4], bfr[4];
#pragma unroll
    for (int m = 0; m < 4; m++)
      af[m] = *(const bf16x8*)&Alds[wm * 64 + m * 16 + (l & 15)][(l >> 4) * 8];
#pragma unroll
    for (int n = 0; n < 4; n++)
      bfr[n] = *(const bf16x8*)&Blds[wn * 64 + n * 16 + (l & 15)][(l >> 4) * 8];
#pragma unroll
    for (int m = 0; m < 4; m++)
#pragma unroll
      for (int n = 0; n < 4; n++) acc[m][n] = mfma16x16(af[m], bfr[n], acc[m][n]);
    __syncthreads();
  }

  const int ccol = l & 15;
  const int crb = (l >> 4) * 4;
  __bf16* Ohm = (z == 0) ? Qh : Kh;
#pragma unroll
  for (int n = 0; n < 4; n++) {
    const int col = c0 + wn * 64 + n * 16 + ccol;
    const float bv = bias[col];
    const int h = col >> 6, d = col & 63;
#pragma unroll
    for (int m = 0; m < 4; m++) {
      const int row = r0 + wm * 64 + m * 16 + crb;
      f32x4 v = acc[m][n];
#pragma unroll
      for (int r = 0; r < 4; r++) v[r] += bv;
      if (z < 2) {  // head-major [b,h,l,d]
#pragma unroll
        for (int r = 0; r < 4; r++) {
          const int rr = row + r; const int bb = rr >> 11; const int ll = rr & 2047;
          Ohm[(((size_t)bb * NH + h) * SEQ + ll) * HD + d] = (__bf16)v[r];
        }
      } else {  // V^T [b,h,d,l]
        const int bb = row >> 11, ll = row & 2047;
        bf16x4 pk;
#pragma unroll
        for (int r = 0; r < 4; r++) pk[r] = (__bf16)v[r];
        *(bf16x4*)&Vt[(((size_t)bb * NH + h) * HD + d) * SEQ + ll] = pk;
      }
    }
  }
}

// ---------------- Pass A: denominators over the HEADS axis -----------------
// Wave-autonomous: one wave = one 32q x 32k tile, loops all 16 heads.
// E' = mfma(K, Q): col = q_local = l&31, row = k_local = (r&3)+8*(r>>2)+4*hi
// Stores Dinv (bf16, [b][k][q]) and bit-packed mask mbit[b][q][k/32].
__global__ __launch_bounds__(512, 2)
void denom_kernel(const __bf16* __restrict__ Qh, const __bf16* __restrict__ Kh,
                  const int* __restrict__ mask, __bf16* __restrict__ Dinv,
                  unsigned* __restrict__ mbit) {
  const int tid = threadIdx.x;
  const int l = tid & 63, w = tid >> 6;
  const int lq = l & 31, hi = l >> 5;
  const int ktg = blockIdx.x;            // 8  (grid.x so each XCD owns a k-chunk)
  const int b = blockIdx.y;              // 2
  const int qt = blockIdx.z;             // 64
  const int q0 = qt * 32;
  const int k0 = (ktg * 8 + w) * 32;     // wave's 32-k tile

  // Build mask word for this lane's q-row over [k0, k0+32)
  unsigned word = 0;
  {
    const i32x4* mp = (const i32x4*)(mask + ((size_t)b * SEQ + q0 + lq) * SEQ + k0);
#pragma unroll
    for (int j = 0; j < 8; j++) {
      const i32x4 v = mp[j];
      word |= (v.x ? 1u : 0u) << (4 * j);
      word |= (v.y ? 1u : 0u) << (4 * j + 1);
      word |= (v.z ? 1u : 0u) << (4 * j + 2);
      word |= (v.w ? 1u : 0u) << (4 * j + 3);
    }
    if (hi == 0) mbit[((size_t)b * SEQ + q0 + lq) * (SEQ / 32) + (k0 >> 5)] = word;
  }

  float dsum[16];
#pragma unroll
  for (int r = 0; r < 16; r++) dsum[r] = 0.0f;

  const __bf16* qbase = Qh + ((size_t)b * NH) * SEQ * HD + (size_t)(q0 + lq) * HD + hi * 8;
  const __bf16* kbase = Kh + ((size_t)b * NH) * SEQ * HD + (size_t)(k0 + lq) * HD + hi * 8;

  for (int h = 0; h < NH; h++) {
    const __bf16* qp = qbase + (size_t)h * SEQ * HD;
    const __bf16* kp = kbase + (size_t)h * SEQ * HD;
    bf16x8 qf[4], kf[4];
#pragma unroll
    for (int ch = 0; ch < 4; ch++) {
      qf[ch] = *(const bf16x8*)(qp + ch * 16);
      kf[ch] = *(const bf16x8*)(kp + ch * 16);
    }
    f32x16 e = zero16();
#pragma unroll
    for (int ch = 0; ch < 4; ch++) e = mfma32x32(kf[ch], qf[ch], e);
#pragma unroll
    for (int r = 0; r < 16; r++) {
      const int crow = (r & 3) + 8 * (r >> 2) + 4 * hi;
      const float bv = ((word >> crow) & 1u) ? 0.0f : -1e10f;
      dsum[r] += __expf(fmaf(e[r], 0.125f, bv));
    }
  }
  // Store reciprocal, transposed: Dinv[b][k][q] (half-wave contiguous per r)
#pragma unroll
  for (int r = 0; r < 16; r++) {
    const int crow = (r & 3) + 8 * (r >> 2) + 4 * hi;
    Dinv[((size_t)b * SEQ + k0 + crow) * SEQ + q0 + lq] =
        (__bf16)__builtin_amdgcn_rcpf(dsum[r]);
  }
}

// ---------------- Pass B: per-head attention, barrier-free ------------------
// One wave = 32 q-rows of one head, sweeps all k. No LDS, no __syncthreads.
__global__ __launch_bounds__(256, 2)
void attn2_kernel(const __bf16* __restrict__ Qh, const __bf16* __restrict__ Kh,
                  const __bf16* __restrict__ Vt, const __bf16* __restrict__ Dinv,
                  const unsigned* __restrict__ mbit, __bf16* __restrict__ X) {
  const int tid = threadIdx.x;
  const int l = tid & 63, w = tid >> 6;  // 4 waves
  const int lq = l & 31, hi = l >> 5;
  const int bh = blockIdx.x;             // 32 (grid.x so a head's blocks share an XCD)
  const int b = bh >> 4;
  const int q0 = (blockIdx.y * 4 + w) * 32;  // grid.y = 16

  // Q fragments (held whole sweep)
  bf16x8 qf[4];
  {
    const __bf16* qp = Qh + ((size_t)bh * SEQ + q0 + lq) * HD + hi * 8;
#pragma unroll
    for (int ch = 0; ch < 4; ch++) qf[ch] = *(const bf16x8*)(qp + ch * 16);
  }
  f32x16 x0 = zero16(), x1 = zero16();

  const __bf16* kbase = Kh + (size_t)bh * SEQ * HD;
  const __bf16* vbase = Vt + (size_t)bh * HD * SEQ;
  const unsigned* mrow = mbit + ((size_t)b * SEQ + q0 + lq) * (SEQ / 32);
  const __bf16* drow = Dinv + (size_t)b * SEQ * SEQ + q0 + lq;  // + k*SEQ

  for (int kt = 0; kt < SEQ / 32; kt++) {
    const int k0 = kt * 32;
    f32x16 e = zero16();
#pragma unroll
    for (int ch = 0; ch < 4; ch++) {
      const bf16x8 kf = *(const bf16x8*)(kbase + (size_t)(k0 + lq) * HD + ch * 16 + hi * 8);
      e = mfma32x32(kf, qf[ch], e);
    }
    const unsigned word = mrow[kt];
    float p[16], rd[16];
#pragma unroll
    for (int r = 0; r < 16; r++) {
      const int crow = (r & 3) + 8 * (r >> 2) + 4 * hi;
      const float bv = ((word >> crow) & 1u) ? 0.0f : -1e10f;
      p[r] = __expf(fmaf(e[r], 0.125f, bv));
      rd[r] = (float)drow[(size_t)(k0 + crow) * SEQ];
    }
    // p * Dinv -> bf16 A-fragments (verbatim from validated process_head)
    unsigned u[8];
#pragma unroll
    for (int j = 0; j < 8; j++) {
      const float a = p[2 * j] * rd[2 * j];
      const float bb2 = p[2 * j + 1] * rd[2 * j + 1];
      u[j] = pkbf(a, bb2);
    }
    unsigned t[8];
#pragma unroll
    for (int j = 0; j < 8; j++) t[j] = (unsigned)__shfl_xor((int)u[j], 32, 64);
    const unsigned w0 = hi ? t[2] : u[0];
    const unsigned w1 = hi ? t[3] : u[1];
    const unsigned w2 = hi ? u[2] : t[0];
    const unsigned w3 = hi ? u[3] : t[1];
    const unsigned w4 = hi ? t[6] : u[4];
    const unsigned w5 = hi ? t[7] : u[5];
    const unsigned w6 = hi ? u[6] : t[4];
    const unsigned w7 = hi ? u[7] : t[5];
    const uint4v s0v = {w0, w1, w2, w3};
    const uint4v s1v = {w4, w5, w6, w7};
    const bf16x8 pa0 = __builtin_bit_cast(bf16x8, s0v);
    const bf16x8 pa1 = __builtin_bit_cast(bf16x8, s1v);
    const __bf16* vp = vbase + (size_t)lq * SEQ + k0 + hi * 8;
    bf16x8 vf;
    vf = *(const bf16x8*)(vp);                         x0 = mfma32x32(pa0, vf, x0);
    vf = *(const bf16x8*)(vp + 16);                    x0 = mfma32x32(pa1, vf, x0);
    vf = *(const bf16x8*)(vp + (size_t)32 * SEQ);      x1 = mfma32x32(pa0, vf, x1);
    vf = *(const bf16x8*)(vp + (size_t)32 * SEQ + 16); x1 = mfma32x32(pa1, vf, x1);
  }

  // Write X (bf16, head-major [b,h,q,d]) — verbatim store pattern from v2
  __bf16* xo = X + ((size_t)bh * SEQ + q0) * HD;
#pragma unroll
  for (int dt = 0; dt < 2; dt++) {
    const f32x16& xx = dt ? x1 : x0;
#pragma unroll
    for (int r = 0; r < 16; r++) {
      const int crow = (r & 3) + 8 * (r >> 2) + 4 * hi;
      xo[(size_t)crow * HD + dt * 32 + lq] = (__bf16)xx[r];
    }
  }
}

// ---------------- O-GEMM: Out[4096,1024] = X[head-major] @ WoT + bo ---------
__global__ __launch_bounds__(256, 4)
void ogemm_kernel(const __bf16* __restrict__ X, const __bf16* __restrict__ Bt,
                  const float* __restrict__ bias, float* __restrict__ Out) {
  __shared__ __bf16 Alds[64][40];
  __shared__ __bf16 Blds[128][40];
  const int tid = threadIdx.x;
  const int l = tid & 63, w = tid >> 6;  // w -> n-offset w*32
  const int r0 = blockIdx.x * 64, c0 = blockIdx.y * 128;

  f32x4 acc[4][2];
#pragma unroll
  for (int m = 0; m < 4; m++)
#pragma unroll
    for (int n = 0; n < 2; n++)
#pragma unroll
      for (int r = 0; r < 4; r++) acc[m][n][r] = 0.0f;

  const int ar = tid >> 2, aq = tid & 3;
  const int br = tid >> 1, bh = tid & 1;
  const int rr = r0 + ar;
  const int bb = rr >> 11, ll = rr & 2047;

  for (int kt = 0; kt < DM / 32; kt++) {
    {
      const int cc = kt * 32 + aq * 8;
      const int h = cc >> 6, d = cc & 63;
      const size_t off = (((size_t)bb * NH + h) * SEQ + ll) * HD + d;
      *(bf16x8*)&Alds[ar][aq * 8] = *(const bf16x8*)(X + off);
    }
    {
      const __bf16* bsrc = Bt + (size_t)(c0 + br) * DM + kt * 32 + bh * 16;
      bf16x8 v0 = *(const bf16x8*)bsrc;
      bf16x8 v1 = *(const bf16x8*)(bsrc + 8);
      *(bf16x8*)&Blds[br][bh * 16] = v0;
      *(bf16x8*)&Blds[br][bh * 16 + 8] = v1;
    }
    __syncthreads();
    bf16x8 af[4], bfr[2];
#pragma unroll
    for (int m = 0; m < 4; m++)
      af[m] = *(const bf16x8*)&Alds[m * 16 + (l & 15)][(l >> 4) * 8];
#pragma unroll
    for (int n = 0; n < 2; n++)
      bfr[n] = *(const bf16x8*)&Blds[w * 32 + n * 16 + (l & 15)][(l >> 4) * 8];
#pragma unroll
    for (int m = 0; m < 4; m++)
#pragma unroll
      for (int n = 0; n < 2; n++) acc[m][n] = mfma16x16(af[m], bfr[n], acc[m][n]);
    __syncthreads();
  }

  const int ccol = l & 15;
  const int crb = (l >> 4) * 4;
#pragma unroll
  for (int n = 0; n < 2; n++) {
    const int col = c0 + w * 32 + n * 16 + ccol;
    const float bv = bias[col];
#pragma unroll
    for (int m = 0; m < 4; m++) {
      const int row = r0 + m * 16 + crb;
      f32x4 v = acc[m][n];
#pragma unroll
      for (int r = 0; r < 4; r++) Out[(size_t)(row + r) * DM + col] = v[r] + bv;
    }
  }
}

// ---------------------------------------------------------------------------
extern "C" void kernel_launch(void* const* d_in, const int* in_sizes, int n_in,
                              void* d_out, int out_size, void* d_ws, size_t ws_size,
                              hipStream_t stream) {
  const float* q = (const float*)d_in[0];
  const float* k = (const float*)d_in[1];
  const float* v = (const float*)d_in[2];
  const int* msk = (const int*)d_in[3];
  const float* Wq = (const float*)d_in[4];
  const float* bq = (const float*)d_in[5];
  const float* Wk = (const float*)d_in[6];
  const float* bk = (const float*)d_in[7];
  const float* Wv = (const float*)d_in[8];
  const float* bv = (const float*)d_in[9];
  const float* Wo = (const float*)d_in[10];
  const float* bo = (const float*)d_in[11];

  char* ws = (char*)d_ws;
  const size_t MB = 1024 * 1024;
  if (ws_size < 64 * MB) return;  // visible failure rather than OOB
  __bf16* Wt = (__bf16*)(ws);               // 4 x 1M bf16 (8 MiB)
  __bf16* Qh = (__bf16*)(ws + 8 * MB);      // [b,h,l,d] 8 MiB
  __bf16* Kh = (__bf16*)(ws + 16 * MB);     // [b,h,l,d] 8 MiB
  __bf16* Vt = (__bf16*)(ws + 24 * MB);     // [b,h,d,l] 8 MiB
  __bf16* X  = (__bf16*)(ws + 32 * MB);     // [b,h,q,d] 8 MiB
  __bf16* Dinv = (__bf16*)(ws + 40 * MB);   // [b][k][q] 16.78 MiB
  unsigned* mbit = (unsigned*)(ws + 57 * MB);  // [b][q][k/32] 1 MiB

  wconv_kernel<<<dim3(32, 32, 4), 256, 0, stream>>>(Wq, Wk, Wv, Wo, Wt);
  qkv_kernel<<<dim3(32, 8, 3), 256, 0, stream>>>(q, k, v, Wt, bq, bk, bv, Qh, Kh, Vt);
  denom_kernel<<<dim3(8, 2, 64), 512, 0, stream>>>(Qh, Kh, msk, Dinv, mbit);
  attn2_kernel<<<dim3(32, 16), 256, 0, stream>>>(Qh, Kh, Vt, Dinv, mbit, X);
  ogemm_kernel<<<dim3(64, 8), 256, 0, stream>>>(X, Wt + (size_t)3 * DM * DM, bo, (float*)d_out);
}